// Round 1
// baseline (1129.193 us; speedup 1.0000x reference)
//
#include <hip/hip_runtime.h>

// Problem constants (fixed by the reference).
#define B_    8
#define S_    4096
#define DIN   2048
#define DOUT  2048
#define P_    256
#define M_    (B_ * S_)   // 32768 rows

// ---------------------------------------------------------------------------
// Kernel 0: meta_bias  mb[b,k] = sum_p meta[b,p]*bias_w[p,k] + bias_b[k]
// 8*2048 outputs, K=256. Trivial cost.
// ---------------------------------------------------------------------------
__global__ __launch_bounds__(256)
void meta_bias_kernel(const float* __restrict__ meta,    // [B,P]
                      const float* __restrict__ bias_w,  // [P,DOUT]
                      const float* __restrict__ bias_b,  // [DOUT]
                      float* __restrict__ mb) {          // [B,DOUT]
    int idx = blockIdx.x * 256 + threadIdx.x;   // grid covers exactly B_*DOUT
    int b = idx / DOUT;
    int k = idx - b * DOUT;
    const float* mrow = meta + b * P_;
    float acc = bias_b[k];
    #pragma unroll 8
    for (int p = 0; p < P_; ++p)
        acc = fmaf(mrow[p], bias_w[p * DOUT + k], acc);
    mb[idx] = acc;
}

// ---------------------------------------------------------------------------
// Stage 1: H[r,p] = meta[b,p] * sum_j X[r,j] * L[p,j]
//   X: [M, DIN] row-major, L: [P, DIN] row-major (both K-contiguous: A*B^T)
// 128x128 tile, BK=32, 256 threads, 8x8 micro-tile.
// ---------------------------------------------------------------------------
__global__ __launch_bounds__(256)
void gemm_s1(const float* __restrict__ X,
             const float* __restrict__ L,
             const float* __restrict__ meta,
             float* __restrict__ H) {
    constexpr int BM = 128, BN = 128, BK = 32;
    constexpr int LDT = BM + 4;  // 132 floats = 528 B, 16B-divisible -> float4 aligned
    __shared__ float As[BK][LDT];
    __shared__ float Bs[BK][LDT];

    const int tid = threadIdx.x;
    const int tx = tid & 15;        // 0..15  -> N
    const int ty = tid >> 4;        // 0..15  -> M
    const int r0 = blockIdx.x * BM; // M tile origin
    const int c0 = blockIdx.y * BN; // N (P) tile origin
    const int bidx = r0 / S_;       // batch index (uniform per block: 4096 % 128 == 0)

    float acc[8][8] = {};

    const float* Xb = X + (size_t)r0 * DIN;
    const float* Lb = L + (size_t)c0 * DIN;

    for (int k0 = 0; k0 < DIN; k0 += BK) {
        // Stage A tile (transpose into LDS): 128 rows x 32 k = 1024 float4
        #pragma unroll
        for (int i = 0; i < 4; ++i) {
            int f   = tid + i * 256;
            int row = f >> 3;             // 8 float4 per row
            int kq  = (f & 7) << 2;
            float4 v = *reinterpret_cast<const float4*>(&Xb[row * DIN + k0 + kq]);
            As[kq + 0][row] = v.x; As[kq + 1][row] = v.y;
            As[kq + 2][row] = v.z; As[kq + 3][row] = v.w;
        }
        // Stage B tile (left, also K-contiguous): transpose into LDS
        #pragma unroll
        for (int i = 0; i < 4; ++i) {
            int f   = tid + i * 256;
            int row = f >> 3;
            int kq  = (f & 7) << 2;
            float4 v = *reinterpret_cast<const float4*>(&Lb[row * DIN + k0 + kq]);
            Bs[kq + 0][row] = v.x; Bs[kq + 1][row] = v.y;
            Bs[kq + 2][row] = v.z; Bs[kq + 3][row] = v.w;
        }
        __syncthreads();

        #pragma unroll
        for (int k = 0; k < BK; ++k) {
            float a[8], b[8];
            *reinterpret_cast<float4*>(a)     = *reinterpret_cast<const float4*>(&As[k][ty * 8]);
            *reinterpret_cast<float4*>(a + 4) = *reinterpret_cast<const float4*>(&As[k][ty * 8 + 4]);
            *reinterpret_cast<float4*>(b)     = *reinterpret_cast<const float4*>(&Bs[k][tx * 8]);
            *reinterpret_cast<float4*>(b + 4) = *reinterpret_cast<const float4*>(&Bs[k][tx * 8 + 4]);
            #pragma unroll
            for (int i = 0; i < 8; ++i)
                #pragma unroll
                for (int j = 0; j < 8; ++j)
                    acc[i][j] = fmaf(a[i], b[j], acc[i][j]);
        }
        __syncthreads();
    }

    // Epilogue: scale by meta[bidx, p] and store H
    const float* mrow = meta + bidx * P_;
    #pragma unroll
    for (int i = 0; i < 8; ++i) {
        int r = r0 + ty * 8 + i;
        float* Hr = H + (size_t)r * P_;
        #pragma unroll
        for (int j0 = 0; j0 < 8; j0 += 4) {
            int p = c0 + tx * 8 + j0;
            float4 v;
            v.x = acc[i][j0 + 0] * mrow[p + 0];
            v.y = acc[i][j0 + 1] * mrow[p + 1];
            v.z = acc[i][j0 + 2] * mrow[p + 2];
            v.w = acc[i][j0 + 3] * mrow[p + 3];
            *reinterpret_cast<float4*>(&Hr[p]) = v;
        }
    }
}

// ---------------------------------------------------------------------------
// Stage 2: O[r,k] = sum_p H[r,p] * R[p,k] + mb[b,k]
//   H: [M, P] row-major (K-contiguous), R: [P, DOUT] row-major (N-contiguous)
// ---------------------------------------------------------------------------
__global__ __launch_bounds__(256)
void gemm_s2(const float* __restrict__ H,
             const float* __restrict__ R,
             const float* __restrict__ mb,
             float* __restrict__ O) {
    constexpr int BM = 128, BN = 128, BK = 32;
    constexpr int LDT = BM + 4;
    __shared__ float As[BK][LDT];
    __shared__ float Bs[BK][LDT];

    const int tid = threadIdx.x;
    const int tx = tid & 15;
    const int ty = tid >> 4;
    const int r0 = blockIdx.x * BM;
    const int c0 = blockIdx.y * BN;
    const int bidx = r0 / S_;

    float acc[8][8] = {};

    const float* Hb = H + (size_t)r0 * P_;

    for (int k0 = 0; k0 < P_; k0 += BK) {   // 8 iterations
        // A tile (H, K-contiguous): transpose into LDS
        #pragma unroll
        for (int i = 0; i < 4; ++i) {
            int f   = tid + i * 256;
            int row = f >> 3;
            int kq  = (f & 7) << 2;
            float4 v = *reinterpret_cast<const float4*>(&Hb[row * P_ + k0 + kq]);
            As[kq + 0][row] = v.x; As[kq + 1][row] = v.y;
            As[kq + 2][row] = v.z; As[kq + 3][row] = v.w;
        }
        // B tile (right, N-contiguous): natural [BK][BN] layout, coalesced
        #pragma unroll
        for (int i = 0; i < 4; ++i) {
            int f    = tid + i * 256;       // 1024 float4: 32 rows x 32 f4/row
            int krow = f >> 5;
            int cq   = (f & 31) << 2;
            float4 v = *reinterpret_cast<const float4*>(&R[(size_t)(k0 + krow) * DOUT + c0 + cq]);
            *reinterpret_cast<float4*>(&Bs[krow][cq]) = v;
        }
        __syncthreads();

        #pragma unroll
        for (int k = 0; k < BK; ++k) {
            float a[8], b[8];
            *reinterpret_cast<float4*>(a)     = *reinterpret_cast<const float4*>(&As[k][ty * 8]);
            *reinterpret_cast<float4*>(a + 4) = *reinterpret_cast<const float4*>(&As[k][ty * 8 + 4]);
            *reinterpret_cast<float4*>(b)     = *reinterpret_cast<const float4*>(&Bs[k][tx * 8]);
            *reinterpret_cast<float4*>(b + 4) = *reinterpret_cast<const float4*>(&Bs[k][tx * 8 + 4]);
            #pragma unroll
            for (int i = 0; i < 8; ++i)
                #pragma unroll
                for (int j = 0; j < 8; ++j)
                    acc[i][j] = fmaf(a[i], b[j], acc[i][j]);
        }
        __syncthreads();
    }

    // Epilogue: add broadcast meta-bias and store output
    const float* mbr = mb + bidx * DOUT;
    #pragma unroll
    for (int i = 0; i < 8; ++i) {
        int r = r0 + ty * 8 + i;
        float* Or = O + (size_t)r * DOUT;
        #pragma unroll
        for (int j0 = 0; j0 < 8; j0 += 4) {
            int c = c0 + tx * 8 + j0;
            float4 v;
            v.x = acc[i][j0 + 0] + mbr[c + 0];
            v.y = acc[i][j0 + 1] + mbr[c + 1];
            v.z = acc[i][j0 + 2] + mbr[c + 2];
            v.w = acc[i][j0 + 3] + mbr[c + 3];
            *reinterpret_cast<float4*>(&Or[c]) = v;
        }
    }
}

// ---------------------------------------------------------------------------
extern "C" void kernel_launch(void* const* d_in, const int* in_sizes, int n_in,
                              void* d_out, int out_size, void* d_ws, size_t ws_size,
                              hipStream_t stream) {
    const float* input  = (const float*)d_in[0];  // [B,S,DIN]
    const float* meta   = (const float*)d_in[1];  // [B,P]
    const float* left   = (const float*)d_in[2];  // [P,DIN]
    const float* right  = (const float*)d_in[3];  // [P,DOUT]
    const float* bias_w = (const float*)d_in[4];  // [P,DOUT]
    const float* bias_b = (const float*)d_in[5];  // [DOUT]
    float* out = (float*)d_out;                   // [B,S,DOUT]

    // Workspace layout: H [M,P] fp32 (33.55 MB), then mb [B,DOUT] (64 KB)
    float* H  = (float*)d_ws;
    float* mb = (float*)((char*)d_ws + (size_t)M_ * P_ * sizeof(float));

    // mb = meta @ bias_w + bias_b
    meta_bias_kernel<<<(B_ * DOUT) / 256, 256, 0, stream>>>(meta, bias_w, bias_b, mb);

    // H = (X @ L^T) * meta
    dim3 g1(M_ / 128, P_ / 128);     // (256, 2)
    gemm_s1<<<g1, 256, 0, stream>>>(input, left, meta, H);

    // O = H @ R + mb
    dim3 g2(M_ / 128, DOUT / 128);   // (256, 16)
    gemm_s2<<<g2, 256, 0, stream>>>(H, right, mb, out);
}

// Round 2
// 593.350 us; speedup vs baseline: 1.9031x; 1.9031x over previous
//
#include <hip/hip_runtime.h>
#include <hip/hip_bf16.h>

#define B_    8
#define S_    4096
#define DIN   2048
#define DOUT  2048
#define P_    256
#define M_    (B_ * S_)   // 32768

typedef __attribute__((ext_vector_type(4))) float f32x4;
typedef __attribute__((ext_vector_type(8))) short bf16x8;
typedef __attribute__((ext_vector_type(4))) short bf16x4;

static __device__ __forceinline__ short f2bs(float x) {
    __hip_bfloat16 h = __float2bfloat16(x);
    return *reinterpret_cast<short*>(&h);
}

// ---------------------------------------------------------------------------
// Prep 1: fp32 -> bf16 flat convert (for `left`). n8 = elems/8.
// ---------------------------------------------------------------------------
__global__ __launch_bounds__(256)
void cvt_bf16_kernel(const float* __restrict__ src, short* __restrict__ dst, int n8) {
    int i = blockIdx.x * 256 + threadIdx.x;
    if (i >= n8) return;
    const float4* s = reinterpret_cast<const float4*>(src) + (size_t)i * 2;
    float4 a = s[0], b = s[1];
    bf16x8 o;
    o[0] = f2bs(a.x); o[1] = f2bs(a.y); o[2] = f2bs(a.z); o[3] = f2bs(a.w);
    o[4] = f2bs(b.x); o[5] = f2bs(b.y); o[6] = f2bs(b.z); o[7] = f2bs(b.w);
    *(reinterpret_cast<bf16x8*>(dst) + i) = o;
}

// ---------------------------------------------------------------------------
// Prep 2: Rt[n][k] = bf16(R[k][n]).  R: [P_=256][DOUT=2048] fp32.
// grid (DOUT/64, P_/64), 256 threads, LDS transpose tile.
// ---------------------------------------------------------------------------
__global__ __launch_bounds__(256)
void transposeR_kernel(const float* __restrict__ R, short* __restrict__ Rt) {
    __shared__ float T[64][65];
    const int n0 = blockIdx.x * 64;   // DOUT dim
    const int k0 = blockIdx.y * 64;   // P dim
    const int tid = threadIdx.x;
    #pragma unroll
    for (int e = 0; e < 16; ++e) {
        int idx = tid + e * 256;
        int r = idx >> 6, c = idx & 63;
        T[r][c] = R[(size_t)(k0 + r) * DOUT + n0 + c];
    }
    __syncthreads();
    #pragma unroll
    for (int e = 0; e < 4; ++e) {
        int g = tid + e * 256;
        int n = g >> 4, k4 = (g & 15) << 2;
        bf16x4 v;
        v[0] = f2bs(T[k4 + 0][n]); v[1] = f2bs(T[k4 + 1][n]);
        v[2] = f2bs(T[k4 + 2][n]); v[3] = f2bs(T[k4 + 3][n]);
        *reinterpret_cast<bf16x4*>(&Rt[(size_t)(n0 + n) * P_ + k0 + k4]) = v;
    }
}

// ---------------------------------------------------------------------------
// Prep 3: mb[b,k] = meta[b,:] @ bias_w[:,k] + bias_b[k]   (tiny, fp32 VALU)
// ---------------------------------------------------------------------------
__global__ __launch_bounds__(256)
void meta_bias_kernel(const float* __restrict__ meta,
                      const float* __restrict__ bias_w,
                      const float* __restrict__ bias_b,
                      float* __restrict__ mb) {
    int idx = blockIdx.x * 256 + threadIdx.x;
    int b = idx / DOUT;
    int k = idx - b * DOUT;
    const float* mrow = meta + b * P_;
    float acc = bias_b[k];
    #pragma unroll 8
    for (int p = 0; p < P_; ++p)
        acc = fmaf(mrow[p], bias_w[p * DOUT + k], acc);
    mb[idx] = acc;
}

// ---------------------------------------------------------------------------
// Main MFMA GEMM:  C[128 x 256 tile] = A (K-contig) x B^T (K-contig, bf16)
//   A_F32: A is fp32, converted to bf16 during staging (stage 1: X).
//          else A is bf16 in memory (stage 2: H).
//   META_EPI: epilogue multiplies by meta[b, col] and stores bf16 H.
//          else epilogue adds mb[b, col] and stores fp32 out.
// 512 threads = 8 waves (2M x 4N), per-wave 64x64, mfma_f32_16x16x32_bf16.
// LDS XOR-swizzle (G4): byte ^= (row&7)<<4 on both write and read.
// ---------------------------------------------------------------------------
template<int KTOT, int LDC, bool A_F32, bool META_EPI>
__global__ __launch_bounds__(512, 2)
void gemm_bt(const void* __restrict__ Ap,
             const short* __restrict__ Bp,
             const float* __restrict__ vvec,
             void* __restrict__ Cp) {
    constexpr int BM = 128, BN = 256, BK = 64;
    __shared__ short As[BM * BK];   // 16 KB
    __shared__ short Bs[BN * BK];   // 32 KB

    const int tid  = threadIdx.x;
    const int lane = tid & 63;
    const int w    = tid >> 6;
    const int wr   = w >> 2;        // 0..1
    const int wc   = w & 3;         // 0..3
    const int lm   = lane & 15;
    const int rg   = lane >> 4;     // 0..3
    const int r0   = blockIdx.x * BM;
    const int c0   = blockIdx.y * BN;
    const int bidx = r0 / S_;       // batch (S_ % BM == 0)

    f32x4 acc[4][4] = {};

    const float* Af = (const float*)Ap;
    const short* Ab = (const short*)Ap;

    for (int k0 = 0; k0 < KTOT; k0 += BK) {
        // ---- stage A tile: 128x64 bf16 = 1024 x 16B chunks, 2/thread ----
        #pragma unroll
        for (int e = 0; e < 2; ++e) {
            int c   = tid + e * 512;
            int row = c >> 3;
            int k8  = (c & 7) << 3;
            int off = ((row * BK + k8) * 2) ^ ((row & 7) << 4);
            bf16x8 o;
            if (A_F32) {
                const float* src = Af + (size_t)(r0 + row) * KTOT + k0 + k8;
                float4 v0 = *reinterpret_cast<const float4*>(src);
                float4 v1 = *reinterpret_cast<const float4*>(src + 4);
                o[0] = f2bs(v0.x); o[1] = f2bs(v0.y); o[2] = f2bs(v0.z); o[3] = f2bs(v0.w);
                o[4] = f2bs(v1.x); o[5] = f2bs(v1.y); o[6] = f2bs(v1.z); o[7] = f2bs(v1.w);
            } else {
                o = *reinterpret_cast<const bf16x8*>(Ab + (size_t)(r0 + row) * KTOT + k0 + k8);
            }
            *reinterpret_cast<bf16x8*>(reinterpret_cast<char*>(As) + off) = o;
        }
        // ---- stage B tile: 256x64 bf16 = 2048 chunks, 4/thread ----
        #pragma unroll
        for (int e = 0; e < 4; ++e) {
            int c   = tid + e * 512;
            int row = c >> 3;
            int k8  = (c & 7) << 3;
            int off = ((row * BK + k8) * 2) ^ ((row & 7) << 4);
            bf16x8 o = *reinterpret_cast<const bf16x8*>(Bp + (size_t)(c0 + row) * KTOT + k0 + k8);
            *reinterpret_cast<bf16x8*>(reinterpret_cast<char*>(Bs) + off) = o;
        }
        __syncthreads();

        // ---- fragments + MFMA ----
        bf16x8 af[4][2], bfr[4][2];
        #pragma unroll
        for (int i = 0; i < 4; ++i)
            #pragma unroll
            for (int kk = 0; kk < 2; ++kk) {
                int m   = wr * 64 + i * 16 + lm;
                int off = ((m * BK + kk * 32 + rg * 8) * 2) ^ ((m & 7) << 4);
                af[i][kk] = *reinterpret_cast<const bf16x8*>(reinterpret_cast<const char*>(As) + off);
            }
        #pragma unroll
        for (int j = 0; j < 4; ++j)
            #pragma unroll
            for (int kk = 0; kk < 2; ++kk) {
                int n   = wc * 64 + j * 16 + lm;
                int off = ((n * BK + kk * 32 + rg * 8) * 2) ^ ((n & 7) << 4);
                bfr[j][kk] = *reinterpret_cast<const bf16x8*>(reinterpret_cast<const char*>(Bs) + off);
            }
        #pragma unroll
        for (int kk = 0; kk < 2; ++kk)
            #pragma unroll
            for (int i = 0; i < 4; ++i)
                #pragma unroll
                for (int j = 0; j < 4; ++j)
                    acc[i][j] = __builtin_amdgcn_mfma_f32_16x16x32_bf16(
                        af[i][kk], bfr[j][kk], acc[i][j], 0, 0, 0);
        __syncthreads();
    }

    // ---- epilogue (C/D layout: col = lane&15, row = (lane>>4)*4 + q) ----
    if (META_EPI) {
        const float* mrow = vvec + bidx * P_;
        short* Hc = (short*)Cp;
        #pragma unroll
        for (int i = 0; i < 4; ++i) {
            int rbase = r0 + wr * 64 + i * 16 + rg * 4;
            #pragma unroll
            for (int j = 0; j < 4; ++j) {
                int col = c0 + wc * 64 + j * 16 + lm;
                float mv = mrow[col];
                #pragma unroll
                for (int q = 0; q < 4; ++q)
                    Hc[(size_t)(rbase + q) * LDC + col] = f2bs(acc[i][j][q] * mv);
            }
        }
    } else {
        const float* mbr = vvec + bidx * DOUT;
        float* Oc = (float*)Cp;
        #pragma unroll
        for (int i = 0; i < 4; ++i) {
            int rbase = r0 + wr * 64 + i * 16 + rg * 4;
            #pragma unroll
            for (int j = 0; j < 4; ++j) {
                int col = c0 + wc * 64 + j * 16 + lm;
                float bv = mbr[col];
                #pragma unroll
                for (int q = 0; q < 4; ++q)
                    Oc[(size_t)(rbase + q) * LDC + col] = acc[i][j][q] + bv;
            }
        }
    }
}

// ---------------------------------------------------------------------------
extern "C" void kernel_launch(void* const* d_in, const int* in_sizes, int n_in,
                              void* d_out, int out_size, void* d_ws, size_t ws_size,
                              hipStream_t stream) {
    const float* input  = (const float*)d_in[0];  // [B,S,DIN]
    const float* meta   = (const float*)d_in[1];  // [B,P]
    const float* left   = (const float*)d_in[2];  // [P,DIN]
    const float* right  = (const float*)d_in[3];  // [P,DOUT]
    const float* bias_w = (const float*)d_in[4];  // [P,DOUT]
    const float* bias_b = (const float*)d_in[5];  // [DOUT]
    float* out = (float*)d_out;                   // [B,S,DOUT]

    // Workspace layout
    char* ws = (char*)d_ws;
    short* H  = (short*)ws;                                   // 16,777,216 B (bf16 [M,P])
    float* mb = (float*)(ws + 16777216);                      // 65,536 B
    short* Lb = (short*)(ws + 16777216 + 65536);              // 1 MB  (bf16 [P,DIN])
    short* Rt = (short*)(ws + 16777216 + 65536 + 1048576);    // 1 MB  (bf16 [DOUT,P])

    cvt_bf16_kernel<<<256, 256, 0, stream>>>(left, Lb, (P_ * DIN) / 8);
    transposeR_kernel<<<dim3(DOUT / 64, P_ / 64), 256, 0, stream>>>(right, Rt);
    meta_bias_kernel<<<(B_ * DOUT) / 256, 256, 0, stream>>>(meta, bias_w, bias_b, mb);

    // Stage 1: H = bf16( (X @ L^T) * meta ).  BN=256 == P so X is read once.
    gemm_bt<DIN, P_, true, true>
        <<<dim3(M_ / 128, 1), 512, 0, stream>>>(input, Lb, meta, H);

    // Stage 2: out = H @ Rt^T + mb
    gemm_bt<P_, DOUT, false, false>
        <<<dim3(M_ / 128, DOUT / 256), 512, 0, stream>>>(H, Rt, mb, out);
}

// Round 3
// 568.960 us; speedup vs baseline: 1.9847x; 1.0429x over previous
//
#include <hip/hip_runtime.h>
#include <hip/hip_bf16.h>
#include <stdint.h>

#define B_    8
#define S_    4096
#define DIN   2048
#define DOUT  2048
#define P_    256
#define M_    (B_ * S_)   // 32768

typedef __attribute__((ext_vector_type(4))) float f32x4;
typedef __attribute__((ext_vector_type(8))) short bf16x8;

static __device__ __forceinline__ short f2bs(float x) {
    __hip_bfloat16 h = __float2bfloat16(x);
    return *reinterpret_cast<short*>(&h);
}

// global -> LDS async DMA, 16 B per lane (wave writes lds_base + lane*16)
static __device__ __forceinline__ void gld_lds16(const void* g, void* l) {
    __builtin_amdgcn_global_load_lds(
        (const __attribute__((address_space(1))) unsigned int*)(uintptr_t)g,
        (__attribute__((address_space(3))) unsigned int*)(uintptr_t)l,
        16, 0, 0);
}

// XOR swizzle: spreads row-major [row][k] bf16 tiles (row stride 128 B) across banks
#define SWZ(row, byteoff) ((byteoff) ^ (((row) & 7) << 4))

// ---------------------------------------------------------------------------
// Prep 1: left [P=256][DIN] fp32 -> bf16 swizzled k-tile images.
// Image kt (32 total, 32 KB each): byte (row*128 + kk*2) ^ ((row&7)<<4).
// ---------------------------------------------------------------------------
__global__ __launch_bounds__(256)
void prep_left(const float* __restrict__ L, char* __restrict__ Lsw) {
    int g = blockIdx.x * 256 + threadIdx.x;        // 65536 chunks of 8
    int row = g >> 8;                              // 0..255
    int c8  = g & 255;                             // 256 chunks/row
    int k = c8 * 8, kt = k >> 6, kk = k & 63;
    const float* src = L + (size_t)row * DIN + k;
    float4 v0 = *reinterpret_cast<const float4*>(src);
    float4 v1 = *reinterpret_cast<const float4*>(src + 4);
    bf16x8 o;
    o[0]=f2bs(v0.x); o[1]=f2bs(v0.y); o[2]=f2bs(v0.z); o[3]=f2bs(v0.w);
    o[4]=f2bs(v1.x); o[5]=f2bs(v1.y); o[6]=f2bs(v1.z); o[7]=f2bs(v1.w);
    int off = kt * 32768 + SWZ(row, row * 128 + kk * 2);
    *reinterpret_cast<bf16x8*>(Lsw + off) = o;
}

// ---------------------------------------------------------------------------
// Prep 2: right [P=256][DOUT] fp32 -> transposed bf16 swizzled images.
// Image (nb, kt) (8*4, 32 KB each): row = n&255, kk = p&63.
// ---------------------------------------------------------------------------
__global__ __launch_bounds__(256)
void prep_right(const float* __restrict__ R, char* __restrict__ Rsw) {
    __shared__ float T[64][65];
    const int n0 = blockIdx.x * 64;   // DOUT dim
    const int p0 = blockIdx.y * 64;   // P dim
    const int tid = threadIdx.x;
    #pragma unroll
    for (int e = 0; e < 16; ++e) {
        int idx = tid + e * 256;
        int r = idx >> 6, c = idx & 63;            // r: p-local, c: n-local
        T[r][c] = R[(size_t)(p0 + r) * DOUT + n0 + c];
    }
    __syncthreads();
    #pragma unroll
    for (int e = 0; e < 2; ++e) {
        int cc = tid + e * 256;                    // 512 chunks
        int nl = cc >> 3, p8 = (cc & 7) * 8;
        bf16x8 o;
        #pragma unroll
        for (int u = 0; u < 8; ++u) o[u] = f2bs(T[p8 + u][nl]);
        int n = n0 + nl;
        int nb = n >> 8, row = n & 255;
        int kt = p0 >> 6, kk = p8;
        int off = (nb * 4 + kt) * 32768 + SWZ(row, row * 128 + kk * 2);
        *reinterpret_cast<bf16x8*>(Rsw + off) = o;
    }
}

// ---------------------------------------------------------------------------
// Prep 3: mb[b,k] = meta[b,:] @ bias_w[:,k] + bias_b[k]   (fp32, vectorized)
// ---------------------------------------------------------------------------
__global__ __launch_bounds__(256)
void meta_bias_kernel(const float* __restrict__ meta,
                      const float* __restrict__ bias_w,
                      const float* __restrict__ bias_b,
                      float* __restrict__ mb) {
    int g = blockIdx.x * 256 + threadIdx.x;        // 4096
    int b  = g >> 9;
    int k4 = (g & 511) * 4;
    const float* mrow = meta + b * P_;
    float4 acc = *reinterpret_cast<const float4*>(&bias_b[k4]);
    #pragma unroll 4
    for (int p = 0; p < P_; ++p) {
        float mval = mrow[p];
        float4 wv = *reinterpret_cast<const float4*>(&bias_w[(size_t)p * DOUT + k4]);
        acc.x = fmaf(mval, wv.x, acc.x);
        acc.y = fmaf(mval, wv.y, acc.y);
        acc.z = fmaf(mval, wv.z, acc.z);
        acc.w = fmaf(mval, wv.w, acc.w);
    }
    *reinterpret_cast<float4*>(&mb[(size_t)b * DOUT + k4]) = acc;
}

// ---------------------------------------------------------------------------
// MFMA GEMM, BM=64 x BN=256, BK=64, 256 threads = 4 waves (wave w -> cols w*64).
//   S1: A = X fp32 (reg-staged + cvt), B = Lsw images; epi: *meta -> H_swz images
//   S2: A = H_swz images (gld_lds), B = Rsw images;    epi: +mb   -> out fp32
// LDS: As 8 KB + Bs 32 KB = 40 KB -> ~3 blocks/CU with __launch_bounds__(256,3).
// ---------------------------------------------------------------------------
template<bool S1>
__global__ __launch_bounds__(256, 3)
void gemm_mfma(const void* __restrict__ Ap,
               const char* __restrict__ Bsw,
               const float* __restrict__ vvec,
               void* __restrict__ Cp) {
    constexpr int KTOT = S1 ? DIN : P_;
    constexpr int NK   = KTOT / 64;            // 32 or 4
    __shared__ short As[64 * 64];
    __shared__ short Bs[256 * 64];

    const int tid  = threadIdx.x;
    const int lane = tid & 63;
    const int w    = tid >> 6;       // 0..3
    const int lm   = lane & 15;
    const int rg   = lane >> 4;      // 0..3
    const int mblk = blockIdx.x;     // 0..511
    const int r0   = mblk * 64;
    const int c0   = S1 ? 0 : blockIdx.y * 256;
    const int bidx = mblk >> 6;      // 64 m-blocks per batch

    f32x4 acc[4][4] = {};
    const float* Xf  = (const float*)Ap;
    const char* Himg = (const char*)Ap;
    char* AsB = (char*)As;
    char* BsB = (char*)Bs;

    for (int kt = 0; kt < NK; ++kt) {
        // ---- B tile: pre-swizzled 32 KB image -> linear LDS (8 calls/wave) ----
        const char* bimg = Bsw + (size_t)(S1 ? kt : ((int)blockIdx.y * NK + kt)) * 32768;
        #pragma unroll
        for (int c = 0; c < 8; ++c)
            gld_lds16(bimg + (w * 8 + c) * 1024 + lane * 16, BsB + (w * 8 + c) * 1024);
        // ---- A tile ----
        if (S1) {
            #pragma unroll
            for (int e = 0; e < 2; ++e) {
                int row = (tid >> 3) + e * 32;           // 0..63
                int k8  = (tid & 7) * 8;
                const float* src = Xf + (size_t)(r0 + row) * DIN + kt * 64 + k8;
                float4 v0 = *reinterpret_cast<const float4*>(src);
                float4 v1 = *reinterpret_cast<const float4*>(src + 4);
                bf16x8 o;
                o[0]=f2bs(v0.x); o[1]=f2bs(v0.y); o[2]=f2bs(v0.z); o[3]=f2bs(v0.w);
                o[4]=f2bs(v1.x); o[5]=f2bs(v1.y); o[6]=f2bs(v1.z); o[7]=f2bs(v1.w);
                *reinterpret_cast<bf16x8*>(AsB + SWZ(row, row * 128 + k8 * 2)) = o;
            }
        } else {
            const char* aimg = Himg + ((size_t)mblk * NK + kt) * 8192;
            #pragma unroll
            for (int c = 0; c < 2; ++c)
                gld_lds16(aimg + (w * 2 + c) * 1024 + lane * 16, AsB + (w * 2 + c) * 1024);
        }
        __syncthreads();

        // ---- fragments + MFMA (kk-split keeps VGPR pressure down) ----
        #pragma unroll
        for (int kk = 0; kk < 2; ++kk) {
            bf16x8 af[4], bfr[4];
            #pragma unroll
            for (int i = 0; i < 4; ++i) {
                int m = i * 16 + lm;
                af[i] = *reinterpret_cast<const bf16x8*>(
                    AsB + SWZ(m, m * 128 + (kk * 32 + rg * 8) * 2));
            }
            #pragma unroll
            for (int j = 0; j < 4; ++j) {
                int n = w * 64 + j * 16 + lm;
                bfr[j] = *reinterpret_cast<const bf16x8*>(
                    BsB + SWZ(n, n * 128 + (kk * 32 + rg * 8) * 2));
            }
            #pragma unroll
            for (int i = 0; i < 4; ++i)
                #pragma unroll
                for (int j = 0; j < 4; ++j)
                    acc[i][j] = __builtin_amdgcn_mfma_f32_16x16x32_bf16(
                        af[i], bfr[j], acc[i][j], 0, 0, 0);
        }
        __syncthreads();
    }

    // ---- epilogue (C/D: col = lane&15, row = rg*4 + q) ----
    if (S1) {
        const float* mrow = vvec + bidx * P_;
        char* Hout = (char*)Cp + (size_t)mblk * 32768;   // 4 k-tile images
        float mv[4];
        #pragma unroll
        for (int j = 0; j < 4; ++j) mv[j] = mrow[w * 64 + j * 16 + lm];
        #pragma unroll
        for (int i = 0; i < 4; ++i) {
            int rb = i * 16 + rg * 4;                    // row within 64
            #pragma unroll
            for (int j = 0; j < 4; ++j) {
                int p = w * 64 + j * 16 + lm;            // 0..255 (stage-2 k)
                int ktile = p >> 6, kk = p & 63;
                #pragma unroll
                for (int q = 0; q < 4; ++q) {
                    int r = rb + q;
                    int off = ktile * 8192 + SWZ(r, r * 128 + kk * 2);
                    *reinterpret_cast<short*>(Hout + off) = f2bs(acc[i][j][q] * mv[j]);
                }
            }
        }
    } else {
        const float* mbr = vvec + bidx * DOUT;
        float* Oc = (float*)Cp;
        float bv[4];
        #pragma unroll
        for (int j = 0; j < 4; ++j) bv[j] = mbr[c0 + w * 64 + j * 16 + lm];
        #pragma unroll
        for (int i = 0; i < 4; ++i) {
            #pragma unroll
            for (int j = 0; j < 4; ++j) {
                int col = c0 + w * 64 + j * 16 + lm;
                #pragma unroll
                for (int q = 0; q < 4; ++q) {
                    int row = r0 + i * 16 + rg * 4 + q;
                    Oc[(size_t)row * DOUT + col] = acc[i][j][q] + bv[j];
                }
            }
        }
    }
}

// ---------------------------------------------------------------------------
extern "C" void kernel_launch(void* const* d_in, const int* in_sizes, int n_in,
                              void* d_out, int out_size, void* d_ws, size_t ws_size,
                              hipStream_t stream) {
    const float* input  = (const float*)d_in[0];  // [B,S,DIN]
    const float* meta   = (const float*)d_in[1];  // [B,P]
    const float* left   = (const float*)d_in[2];  // [P,DIN]
    const float* right  = (const float*)d_in[3];  // [P,DOUT]
    const float* bias_w = (const float*)d_in[4];  // [P,DOUT]
    const float* bias_b = (const float*)d_in[5];  // [DOUT]
    float* out = (float*)d_out;                   // [B,S,DOUT]

    // Workspace: Hsw 16 MB (512 mblk x 4 kt x 8 KB) | mb 64 KB | Lsw 1 MB | Rsw 1 MB
    char* ws  = (char*)d_ws;
    char* Hsw = ws;
    float* mb = (float*)(ws + 16777216);
    char* Lsw = ws + 16777216 + 65536;
    char* Rsw = Lsw + 1048576;

    prep_left <<<256, 256, 0, stream>>>(left, Lsw);
    prep_right<<<dim3(DOUT / 64, P_ / 64), 256, 0, stream>>>(right, Rsw);
    meta_bias_kernel<<<16, 256, 0, stream>>>(meta, bias_w, bias_b, mb);

    // Stage 1: Hsw = swizzled bf16( (X @ L^T) * meta );  X read exactly once
    gemm_mfma<true><<<dim3(M_ / 64, 1), 256, 0, stream>>>(input, Lsw, meta, Hsw);

    // Stage 2: out = H @ R + mb
    gemm_mfma<false><<<dim3(M_ / 64, DOUT / 256), 256, 0, stream>>>(Hsw, Rsw, mb, out);
}